// Round 2
// 120.474 us; speedup vs baseline: 1.3689x; 1.3689x over previous
//
#include <hip/hip_runtime.h>

typedef __bf16 bf16;
typedef __bf16 bf16x4 __attribute__((ext_vector_type(4)));
typedef __bf16 bf16x8 __attribute__((ext_vector_type(8)));
typedef float  f32x4  __attribute__((ext_vector_type(4)));
typedef unsigned int uint32;

#define BT 64

// ---- bf16 workspace layout (element offsets) ----
#define N_E0 (339*128)
#define N_E1 (5825*128)
#define N_E2 (64*128)
#define N_W1 (256*128)
#define N_W2 (256*768)
#define N_F1 (256*256)
#define N_F2 256
#define O_E0 0
#define O_E1 (O_E0+N_E0)
#define O_E2 (O_E1+N_E1)
#define O_W1 (O_E2+N_E2)
#define O_W2 (O_W1+N_W1)   // w2 TRANSPOSED: [d][m*256+c]
#define O_F1 (O_W2+N_W2)   // wfc1 in MFMA-fragment order: F[e>>4][k>>5][(k>>3)&3][e&15][k&7]
#define O_F2 (O_F1+N_F1)
#define N_TOT (O_F2+N_F2)  // 1,092,352 bf16

#define BYTES_BF16 ((size_t)N_TOT*2)
#define OFF_FLOAT  BYTES_BF16              // f32: b1(256) b2(256) bfc1(256) bfc2(1)
#define OFF_FLAG   (OFF_FLOAT + 772*4)
#define OFF_IDX    (OFF_FLAG + 16)         // int32 idx (131072*3)
#define N_IDX      (131072*3)
#define OFF_Q      (OFF_IDX + (size_t)N_IDX*4)

// Q tables (bf16): Q_m[i][d], 6228 rows total -> 3.19 MB (L2-resident)
#define QB0 0
#define QB1 (339*256)
#define QB2 (QB1 + 5825*256)

static __device__ __forceinline__ f32x4 mfma16(bf16x8 a, bf16x8 b, f32x4 c) {
    return __builtin_amdgcn_mfma_f32_16x16x32_bf16(a, b, c, 0, 0, 0);
}

// ---- normalization. Block ranges: [0,256) idx; [256,768) straight-copy;
// [768,1008) w2-transpose; 1008 biases+flag. Probes per block (deterministic).
__global__ __launch_bounds__(256)
void convert_all(const void* __restrict__ e0, const void* __restrict__ e1,
                 const void* __restrict__ e2, const void* __restrict__ w1r,
                 const void* __restrict__ b1r, const void* __restrict__ w2r,
                 const void* __restrict__ b2r, const void* __restrict__ f1r,
                 const void* __restrict__ fc1br, const void* __restrict__ f2r,
                 const void* __restrict__ fc2br, const void* __restrict__ idxr,
                 bf16* __restrict__ wsb, float* __restrict__ wsf,
                 int* __restrict__ flagp, int* __restrict__ idx32)
{
    __shared__ int sF;
    const int tid = threadIdx.x;
    const int bid = blockIdx.x;
    if (tid == 0) sF = 0;
    __syncthreads();

    if (bid < 256) {
        // i64 probe: int64 index buffers (values < 2^31) have all-zero odd words
        if (((const uint32*)idxr)[tid * 2 + 1] != 0) atomicOr(&sF, 1);
        __syncthreads();
        const bool i64 = (sF == 0);
        #pragma unroll
        for (int it = 0; it < 6; ++it) {
            int k = bid * 1536 + it * 256 + tid;
            if (k < N_IDX) {
                long long v = i64 ? ((const long long*)idxr)[k]
                                  : (long long)((const int*)idxr)[k];
                int m = k - (k / 3) * 3;
                long long dim = (m == 0 ? 339 : (m == 1 ? 5825 : 64));
                v = v < 0 ? 0 : (v >= dim ? dim - 1 : v);
                idx32[k] = (int)v;
            }
        }
        return;
    }

    // fp32 probe: low 16 bits of word as bf16 with exp>126 impossible for |w1|<=0.37
    if (tid < 64) {
        uint32 e = (((const uint32*)w1r)[tid] >> 7) & 0xffu;
        if (e > 126u) atomicOr(&sF, 1);
    }
    __syncthreads();
    const bool fp32 = (sF != 0);

    if (bid < 768) {
        // straight-copy: [0,O_W2) = e0|e1|e2|w1 and [O_F1,N_TOT) = f1|f2, vec4.
        // f1 (wfc1) writes are remapped into MFMA-fragment order so costco_main's
        // B-fragment loads become lane-linear (coalesced).
        const unsigned n4 = (O_W2 + (N_TOT - O_F1)) / 4;
        for (unsigned u = (bid - 256) * 256u + tid; u < n4; u += 512u * 256u) {
            unsigned e = u * 4, dst = e;
            const void* src; unsigned off;
            if (e < O_W2) {
                if (e < O_E1)      { src = e0;  off = e; }
                else if (e < O_E2) { src = e1;  off = e - O_E1; }
                else if (e < O_W1) { src = e2;  off = e - O_E2; }
                else               { src = w1r; off = e - O_W1; }
            } else {
                dst = O_F1 + (e - O_W2);
                if (dst < O_F2) {
                    src = f1r; off = dst - O_F1;
                    // fragment reorder: element (ee,kk) -> F[ee>>4][kk>>5][(kk>>3)&3][ee&15][kk&7]
                    unsigned ee = off >> 8, kk = off & 255u;
                    dst = O_F1 + ((((ee >> 4) * 8u + (kk >> 5)) * 64u
                                   + ((kk >> 3) & 3u) * 16u + (ee & 15u)) << 3) + (kk & 7u);
                } else { src = f2r; off = dst - O_F2; }
            }
            if (fp32) {
                float4 v = *(const float4*)((const float*)src + off);
                bf16x4 o; o[0]=(bf16)v.x; o[1]=(bf16)v.y; o[2]=(bf16)v.z; o[3]=(bf16)v.w;
                *(bf16x4*)(wsb + dst) = o;
            } else {
                *(uint2*)(wsb + dst) = *(const uint2*)((const bf16*)src + off);
            }
        }
    } else if (bid < 1008) {
        // w2t[d][m*256+c] = w2[d][c][m]
        for (unsigned i = (bid - 768) * 256u + tid; i < (unsigned)N_W2; i += 240u * 256u) {
            unsigned d = i / 768u, r = i - d * 768u;
            unsigned m = r >> 8, c = r & 255u;
            unsigned off = d * 768u + c * 3u + m;
            wsb[O_W2 + i] = fp32 ? (bf16)((const float*)w2r)[off] : ((const bf16*)w2r)[off];
        }
    } else {
        if (tid == 0) *flagp = fp32 ? 1 : 0;
        #pragma unroll
        for (int it = 0; it < 4; ++it) {
            int j = it * 256 + tid;
            if (j < 769) {
                const void* src; int off;
                if (j < 256)      { src = b1r;   off = j; }
                else if (j < 512) { src = b2r;   off = j - 256; }
                else if (j < 768) { src = fc1br; off = j - 512; }
                else              { src = fc2br; off = 0; }
                wsf[j] = fp32 ? ((const float*)src)[off] : (float)((const bf16*)src)[off];
            }
        }
    }
}

// ---- build Q tables: Q_m[i][d] = sum_c relu(<emb_m[i],w1[c]>+b1[c]) * w2t[d][m*256+c]
// 99 blocks x 64 table rows. Runs once; tiny (1.2 GF).
__global__ __launch_bounds__(256, 2)
void build_q(const bf16* __restrict__ wsb, const float* __restrict__ wsf,
             bf16* __restrict__ Qt)
{
    __shared__ alignas(16) bf16 sX[64 * 136];
    __shared__ alignas(16) bf16 sPE[64 * 264];

    const int tid  = threadIdx.x;
    const int wave = tid >> 6;
    const int lane = tid & 63;
    const int quad = lane >> 4;
    const int l15  = lane & 15;
    const int bid  = blockIdx.x;

    int m, row0, dim, embBase, qBase;
    if (bid < 6)       { m = 0; row0 = bid * 64;        dim = 339;  embBase = O_E0; qBase = QB0; }
    else if (bid < 98) { m = 1; row0 = (bid - 6) * 64;  dim = 5825; embBase = O_E1; qBase = QB1; }
    else               { m = 2; row0 = 0;               dim = 64;   embBase = O_E2; qBase = QB2; }

    const bf16* w1  = wsb + O_W1;
    const bf16* w2t = wsb + O_W2;
    const float* fb1 = wsf;

    // load 64 emb rows (clamped) into sX
    {
        int row = tid >> 2, seg = tid & 3;
        int r = row0 + row; r = r >= dim ? dim - 1 : r;
        const uint4* s4 = (const uint4*)(wsb + embBase + (size_t)r * 128 + seg * 32);
        uint4* d4 = (uint4*)(&sX[row * 136 + seg * 32]);
        #pragma unroll
        for (int u = 0; u < 4; ++u) d4[u] = s4[u];
    }
    __syncthreads();

    const f32x4 zero4 = {0.f, 0.f, 0.f, 0.f};

    // PE tile: A=w1 rows c (M), B=sX rows (N). D row=c, col=table-row.
    #pragma unroll
    for (int mtl = 0; mtl < 4; ++mtl) {
        int mt = wave * 4 + mtl;
        int c  = mt * 16 + l15;
        bf16x8 aw[4];
        #pragma unroll
        for (int ks = 0; ks < 4; ++ks)
            aw[ks] = *(const bf16x8*)(w1 + c * 128 + ks * 32 + quad * 8);
        const float4 bv = *(const float4*)(fb1 + mt * 16 + quad * 4);
        #pragma unroll
        for (int nt = 0; nt < 4; ++nt) {
            f32x4 acc = zero4;
            #pragma unroll
            for (int ks = 0; ks < 4; ++ks) {
                bf16x8 xb = *(const bf16x8*)(&sX[(nt * 16 + l15) * 136 + ks * 32 + quad * 8]);
                acc = mfma16(aw[ks], xb, acc);
            }
            bf16x4 hv;
            hv[0] = (bf16)fmaxf(acc[0] + bv.x, 0.f);
            hv[1] = (bf16)fmaxf(acc[1] + bv.y, 0.f);
            hv[2] = (bf16)fmaxf(acc[2] + bv.z, 0.f);
            hv[3] = (bf16)fmaxf(acc[3] + bv.w, 0.f);
            *(bf16x4*)(&sPE[(nt * 16 + l15) * 264 + mt * 16 + quad * 4]) = hv;
        }
    }
    __syncthreads();

    // Q tile: A=sPE rows (table rows, M), B=w2t rows d (N). No bias, NO relu.
    f32x4 acc2[4][4];
    #pragma unroll
    for (int i = 0; i < 4; ++i)
        #pragma unroll
        for (int j = 0; j < 4; ++j) acc2[i][j] = zero4;
    #pragma unroll
    for (int ks = 0; ks < 8; ++ks) {
        bf16x8 af[4], bfr[4];
        #pragma unroll
        for (int mt = 0; mt < 4; ++mt)
            af[mt] = *(const bf16x8*)(&sPE[(mt * 16 + l15) * 264 + ks * 32 + quad * 8]);
        #pragma unroll
        for (int nt = 0; nt < 4; ++nt) {
            int d = wave * 64 + nt * 16 + l15;
            bfr[nt] = *(const bf16x8*)(w2t + d * 768 + m * 256 + ks * 32 + quad * 8);
        }
        #pragma unroll
        for (int mt = 0; mt < 4; ++mt)
            #pragma unroll
            for (int nt = 0; nt < 4; ++nt)
                acc2[mt][nt] = mfma16(af[mt], bfr[nt], acc2[mt][nt]);
    }
    #pragma unroll
    for (int nt = 0; nt < 4; ++nt) {
        int d = wave * 64 + nt * 16 + l15;
        #pragma unroll
        for (int mt = 0; mt < 4; ++mt)
            #pragma unroll
            for (int r = 0; r < 4; ++r) {
                int rl = mt * 16 + quad * 4 + r;
                if (row0 + rl < dim)
                    Qt[qBase + (size_t)(row0 + rl) * 256 + d] = (bf16)acc2[mt][nt][r];
            }
    }
}

// ---- main: h2 = relu(Q0[i0]+Q1[i1]+Q2[i2]+b2); h3 = relu(h2 Wfc1^T + bfc1);
// ---- out = relu(h3.wfc2 + bfc2). 64 rows/block, ~34 KB LDS, 4 blocks/CU.
// Gather: half-wave per row -> fully coalesced 512B row reads (8 lines/instr
// instead of 64-line spray). wfc1 read in fragment order (lane-linear).
__global__ __launch_bounds__(256, 4)
void costco_main(const bf16* __restrict__ wsb, const bf16* __restrict__ Qt,
                 const float* __restrict__ wsf, const int* __restrict__ flagp,
                 const int* __restrict__ idx32, void* __restrict__ out)
{
    __shared__ alignas(16) bf16 sH2[BT * 264];
    __shared__ float sRed[BT];
    __shared__ int sIdx[BT * 3];

    const bf16* wf   = wsb + O_F1;   // fragment-ordered wfc1
    const bf16* wfc2 = wsb + O_F2;
    const float* fb2  = wsf + 256;
    const float* fbc1 = wsf + 512;
    const float  bfc2v = wsf[768];
    const int fp32out = *flagp;

    const int tid  = threadIdx.x;
    const int wave = tid >> 6;
    const int lane = tid & 63;
    const int quad = lane >> 4;
    const int l15  = lane & 15;
    const int bbase = blockIdx.x * BT;

    if (tid < BT * 3) sIdx[tid] = idx32[bbase * 3 + tid];
    if (tid < BT) sRed[tid] = bfc2v;
    __syncthreads();

    // gather + sum + bias + relu -> sH2. Half-wave (32 lanes) per row:
    // lane l31 holds elems [l31*8, l31*8+8) -> consecutive 16B chunks, 512B/row.
    {
        const int half = lane >> 5;
        const int l31  = lane & 31;
        float bb[8];
        {
            float4 t0 = *(const float4*)(fb2 + l31 * 8);
            float4 t1 = *(const float4*)(fb2 + l31 * 8 + 4);
            bb[0]=t0.x; bb[1]=t0.y; bb[2]=t0.z; bb[3]=t0.w;
            bb[4]=t1.x; bb[5]=t1.y; bb[6]=t1.z; bb[7]=t1.w;
        }
        #pragma unroll
        for (int rp = 0; rp < 8; ++rp) {
            const int r  = wave * 16 + rp * 2 + half;
            const int i0 = sIdx[r * 3 + 0];
            const int i1 = sIdx[r * 3 + 1];
            const int i2 = sIdx[r * 3 + 2];
            bf16x8 a = *(const bf16x8*)(Qt + QB0 + (size_t)i0 * 256 + l31 * 8);
            bf16x8 b = *(const bf16x8*)(Qt + QB1 + (size_t)i1 * 256 + l31 * 8);
            bf16x8 c = *(const bf16x8*)(Qt + QB2 + (size_t)i2 * 256 + l31 * 8);
            bf16x8 o;
            #pragma unroll
            for (int j = 0; j < 8; ++j) {
                float v = (float)a[j] + (float)b[j] + (float)c[j] + bb[j];
                o[j] = (bf16)fmaxf(v, 0.f);
            }
            *(bf16x8*)(&sH2[r * 264 + l31 * 8]) = o;
        }
    }
    __syncthreads();

    const f32x4 zero4 = {0.f, 0.f, 0.f, 0.f};

    // Stage C: h3 = relu(h2 Wfc1^T + bfc1), waves split N(e).
    // B-fragment loads are lane-linear from the fragment-ordered wfc1.
    f32x4 acc3[4][4];
    #pragma unroll
    for (int i = 0; i < 4; ++i)
        #pragma unroll
        for (int j = 0; j < 4; ++j) acc3[i][j] = zero4;
    #pragma unroll
    for (int ks = 0; ks < 8; ++ks) {
        bf16x8 af[4], bfr[4];
        #pragma unroll
        for (int mt = 0; mt < 4; ++mt)
            af[mt] = *(const bf16x8*)(&sH2[(mt * 16 + l15) * 264 + ks * 32 + quad * 8]);
        #pragma unroll
        for (int nt = 0; nt < 4; ++nt)
            bfr[nt] = *(const bf16x8*)(wf + ((size_t)((wave * 4 + nt) * 8 + ks) * 64 + lane) * 8);
        #pragma unroll
        for (int mt = 0; mt < 4; ++mt)
            #pragma unroll
            for (int nt = 0; nt < 4; ++nt)
                acc3[mt][nt] = mfma16(af[mt], bfr[nt], acc3[mt][nt]);
    }

    // Stage D
    float wv[4], bc[4];
    #pragma unroll
    for (int nt = 0; nt < 4; ++nt) {
        int e = wave * 64 + nt * 16 + l15;
        wv[nt] = (float)wfc2[e];
        bc[nt] = fbc1[e];
    }
    #pragma unroll
    for (int mt = 0; mt < 4; ++mt)
        #pragma unroll
        for (int r = 0; r < 4; ++r) {
            float p = 0.f;
            #pragma unroll
            for (int nt = 0; nt < 4; ++nt)
                p += fmaxf(acc3[mt][nt][r] + bc[nt], 0.f) * wv[nt];
            p += __shfl_xor(p, 1, 64);
            p += __shfl_xor(p, 2, 64);
            p += __shfl_xor(p, 4, 64);
            p += __shfl_xor(p, 8, 64);
            if (l15 == 0) atomicAdd(&sRed[mt * 16 + quad * 4 + r], p);
        }
    __syncthreads();

    if (tid < BT) {
        float v = fmaxf(sRed[tid], 0.f);
        if (fp32out) ((float*)out)[bbase + tid] = v;
        else         ((bf16*)out)[bbase + tid] = (bf16)v;
    }
}

extern "C" void kernel_launch(void* const* d_in, const int* in_sizes, int n_in,
                              void* d_out, int out_size, void* d_ws, size_t ws_size,
                              hipStream_t stream) {
    char* ws = (char*)d_ws;
    bf16*  wsb   = (bf16*)ws;
    float* wsf   = (float*)(ws + OFF_FLOAT);
    int*   flagp = (int*)(ws + OFF_FLAG);
    int*   idx32 = (int*)(ws + OFF_IDX);
    bf16*  Qt    = (bf16*)(ws + OFF_Q);

    hipLaunchKernelGGL(convert_all, dim3(1009), dim3(256), 0, stream,
                       d_in[1], d_in[2], d_in[3], d_in[4], d_in[5], d_in[6],
                       d_in[7], d_in[8], d_in[9], d_in[10], d_in[11], d_in[0],
                       wsb, wsf, flagp, idx32);

    hipLaunchKernelGGL(build_q, dim3(99), dim3(256), 0, stream, wsb, wsf, Qt);

    const int B = 131072;
    hipLaunchKernelGGL(costco_main, dim3(B / BT), dim3(256), 0, stream,
                       wsb, Qt, wsf, flagp, idx32, d_out);
}

// Round 3
// 117.840 us; speedup vs baseline: 1.3995x; 1.0224x over previous
//
#include <hip/hip_runtime.h>

typedef __bf16 bf16;
typedef __bf16 bf16x4 __attribute__((ext_vector_type(4)));
typedef __bf16 bf16x8 __attribute__((ext_vector_type(8)));
typedef float  f32x4  __attribute__((ext_vector_type(4)));
typedef unsigned int uint32;

#define BT 64

// ---- bf16 workspace layout (element offsets) ----
// All build_q operands stored in MFMA-fragment order:
//   frag(ee,kk,NKS): (((ee>>4)*NKS + (kk>>5))*64 + ((kk>>3)&3)*16 + (ee&15))*8 + (kk&7)
// EF*: emb tables, 16-row tiles (2048 elems/tile), padded to tile count.
#define N_EF0 (22*2048)
#define N_EF1 (365*2048)
#define N_EF2 (4*2048)
#define O_EF0 0
#define O_EF1 (O_EF0+N_EF0)      // 45056
#define O_EF2 (O_EF1+N_EF1)      // 792576
#define O_W1F (O_EF2+N_EF2)      // 800768  w1 fragment order (NKS=4)
#define O_W2F (O_W1F+32768)      // 833536  w2 per-mode fragment order [m][dt][ks][lane][8]
#define O_F1  (O_W2F+196608)     // 1030144 wfc1 fragment order (NKS=8)
#define O_F2  (O_F1+65536)       // 1095680 wfc2
#define N_TOT (O_F2+256)         // 1095936 bf16

#define BYTES_BF16 ((size_t)N_TOT*2)
#define OFF_FLOAT  BYTES_BF16              // f32: b1(256) b2(256) bfc1(256) bfc2(1)
#define OFF_FLAG   (OFF_FLOAT + 772*4)
#define OFF_IDX    (OFF_FLAG + 16)         // int32 idx (131072*3)
#define N_IDX      (131072*3)
#define OFF_Q      (OFF_IDX + (size_t)N_IDX*4)

// Q tables (bf16): Q_m[i][d], 6228 rows total -> 3.19 MB (L2-resident)
#define QB0 0
#define QB1 (339*256)
#define QB2 (QB1 + 5825*256)

static __device__ __forceinline__ f32x4 mfma16(bf16x8 a, bf16x8 b, f32x4 c) {
    return __builtin_amdgcn_mfma_f32_16x16x32_bf16(a, b, c, 0, 0, 0);
}

static __device__ __forceinline__ unsigned frag_off(unsigned ee, unsigned kk, unsigned nks) {
    return (((ee >> 4) * nks + (kk >> 5)) * 64u + ((kk >> 3) & 3u) * 16u + (ee & 15u)) * 8u
           + (kk & 7u);
}

// ---- normalization. Block ranges: [0,256) idx; [256,768) fragment-copy;
// [768,1008) w2 fragment-transpose; 1008 biases+flag.
__global__ __launch_bounds__(256)
void convert_all(const void* __restrict__ e0, const void* __restrict__ e1,
                 const void* __restrict__ e2, const void* __restrict__ w1r,
                 const void* __restrict__ b1r, const void* __restrict__ w2r,
                 const void* __restrict__ b2r, const void* __restrict__ f1r,
                 const void* __restrict__ fc1br, const void* __restrict__ f2r,
                 const void* __restrict__ fc2br, const void* __restrict__ idxr,
                 bf16* __restrict__ wsb, float* __restrict__ wsf,
                 int* __restrict__ flagp, int* __restrict__ idx32)
{
    __shared__ int sF;
    const int tid = threadIdx.x;
    const int bid = blockIdx.x;
    if (tid == 0) sF = 0;
    __syncthreads();

    if (bid < 256) {
        // i64 probe: int64 index buffers (values < 2^31) have all-zero odd words
        if (((const uint32*)idxr)[tid * 2 + 1] != 0) atomicOr(&sF, 1);
        __syncthreads();
        const bool i64 = (sF == 0);
        #pragma unroll
        for (int it = 0; it < 6; ++it) {
            int k = bid * 1536 + it * 256 + tid;
            if (k < N_IDX) {
                long long v = i64 ? ((const long long*)idxr)[k]
                                  : (long long)((const int*)idxr)[k];
                int m = k - (k / 3) * 3;
                long long dim = (m == 0 ? 339 : (m == 1 ? 5825 : 64));
                v = v < 0 ? 0 : (v >= dim ? dim - 1 : v);
                idx32[k] = (int)v;
            }
        }
        return;
    }

    // fp32 probe: low 16 bits of word as bf16 with exp>126 impossible for |w1|<=0.37
    if (tid < 64) {
        uint32 e = (((const uint32*)w1r)[tid] >> 7) & 0xffu;
        if (e > 126u) atomicOr(&sF, 1);
    }
    __syncthreads();
    const bool fp32 = (sF != 0);

    if (bid < 768) {
        // fragment-copy, source-linear in 4-elt chunks (all region sizes %4==0).
        // cum: e0 43392 | e1 788992 | e2 797184 | w1 829952 | f1 895488 | f2 895744
        const unsigned n4 = 895744u / 4u;
        for (unsigned u = (bid - 256) * 256u + tid; u < n4; u += 512u * 256u) {
            unsigned e = u * 4;
            const void* src; unsigned off, dst;
            if (e < 829952u) {   // emb/w1: fragment NKS=4
                unsigned base;
                if (e < 43392u)       { src = e0;  off = e;           base = O_EF0; }
                else if (e < 788992u) { src = e1;  off = e - 43392u;  base = O_EF1; }
                else if (e < 797184u) { src = e2;  off = e - 788992u; base = O_EF2; }
                else                  { src = w1r; off = e - 797184u; base = O_W1F; }
                dst = base + frag_off(off >> 7, off & 127u, 4u);
            } else if (e < 895488u) {  // wfc1: fragment NKS=8
                src = f1r; off = e - 829952u;
                dst = O_F1 + frag_off(off >> 8, off & 255u, 8u);
            } else {                   // wfc2 straight
                src = f2r; off = e - 895488u; dst = O_F2 + off;
            }
            if (fp32) {
                float4 v = *(const float4*)((const float*)src + off);
                bf16x4 o; o[0]=(bf16)v.x; o[1]=(bf16)v.y; o[2]=(bf16)v.z; o[3]=(bf16)v.w;
                *(bf16x4*)(wsb + dst) = o;
            } else {
                *(uint2*)(wsb + dst) = *(const uint2*)((const bf16*)src + off);
            }
        }
    } else if (bid < 1008) {
        // W2F[m][dt][ks][lane][j] = w2[d][c][m], d=dt*16+(lane&15), c=ks*32+(lane>>4)*8+j
        for (unsigned i = (bid - 768) * 256u + tid; i < 196608u; i += 240u * 256u) {
            unsigned m = i >> 16, r = i & 65535u;
            unsigned dt = r >> 12, ks = (r >> 9) & 7u, lane = (r >> 3) & 63u, j = r & 7u;
            unsigned d = dt * 16u + (lane & 15u);
            unsigned c = ks * 32u + (lane >> 4) * 8u + j;
            unsigned off = d * 768u + c * 3u + m;
            wsb[O_W2F + i] = fp32 ? (bf16)((const float*)w2r)[off] : ((const bf16*)w2r)[off];
        }
    } else {
        if (tid == 0) *flagp = fp32 ? 1 : 0;
        #pragma unroll
        for (int it = 0; it < 4; ++it) {
            int j = it * 256 + tid;
            if (j < 769) {
                const void* src; int off;
                if (j < 256)      { src = b1r;   off = j; }
                else if (j < 512) { src = b2r;   off = j - 256; }
                else if (j < 768) { src = fc1br; off = j - 512; }
                else              { src = fc2br; off = 0; }
                wsf[j] = fp32 ? ((const float*)src)[off] : (float)((const bf16*)src)[off];
            }
        }
    }
}

// ---- build Q tables: Q_m[i][d] = sum_c relu(<emb_m[i],w1[c]>+b1[c]) * w2[d][c][m]
// One 16-row tile per block -> 391 blocks. All global loads lane-linear
// (fragment-ordered operands); sPE 8KB in stage-Q fragment order.
// Padded tile rows (>= dim) produce garbage columns/rows that are never stored.
__global__ __launch_bounds__(256)
void build_q(const bf16* __restrict__ wsb, const float* __restrict__ wsf,
             bf16* __restrict__ Qt)
{
    __shared__ alignas(16) bf16 sPE[4096];

    const int tid  = threadIdx.x;
    const int wave = tid >> 6;
    const int lane = tid & 63;
    const int quad = lane >> 4;
    const int l15  = lane & 15;
    const int bid  = blockIdx.x;

    int m, tile, dim, efBase, qBase;
    if (bid < 22)       { m = 0; tile = bid;       dim = 339;  efBase = O_EF0; qBase = QB0; }
    else if (bid < 387) { m = 1; tile = bid - 22;  dim = 5825; efBase = O_EF1; qBase = QB1; }
    else                { m = 2; tile = bid - 387; dim = 64;   efBase = O_EF2; qBase = QB2; }
    const int row0 = tile * 16;

    const bf16* w1f = wsb + O_W1F;
    const bf16* w2f = wsb + O_W2F + m * 65536;
    const float* fb1 = wsf;
    const f32x4 zero4 = {0.f, 0.f, 0.f, 0.f};

    // emb B-fragments for this tile (shared across all mt)
    bf16x8 be[4];
    #pragma unroll
    for (int ks = 0; ks < 4; ++ks)
        be[ks] = *(const bf16x8*)(wsb + efBase + (size_t)((tile * 4 + ks) * 64 + lane) * 8);

    // Stage PE: H[c][row] = relu(w1.emb^T + b1); write into stage-Q A-fragment layout.
    #pragma unroll
    for (int mtl = 0; mtl < 4; ++mtl) {
        int mt = wave * 4 + mtl;
        f32x4 acc = zero4;
        #pragma unroll
        for (int ks = 0; ks < 4; ++ks) {
            bf16x8 aw = *(const bf16x8*)(w1f + ((mt * 4 + ks) * 64 + lane) * 8);
            acc = mfma16(aw, be[ks], acc);
        }
        const float4 bv = *(const float4*)(fb1 + mt * 16 + quad * 4);
        bf16x4 hv;
        hv[0] = (bf16)fmaxf(acc[0] + bv.x, 0.f);
        hv[1] = (bf16)fmaxf(acc[1] + bv.y, 0.f);
        hv[2] = (bf16)fmaxf(acc[2] + bv.z, 0.f);
        hv[3] = (bf16)fmaxf(acc[3] + bv.w, 0.f);
        // element (row=l15, c=mt*16+quad*4+r) -> A-frag (ks=c>>5, quadq=(c>>3)&3, j=c&7)
        int ksq   = mt >> 1;
        int quadq = ((mt & 1) << 1) | (quad >> 1);
        int j0    = (quad & 1) * 4;
        *(bf16x4*)(&sPE[(ksq * 64 + quadq * 16 + l15) * 8 + j0]) = hv;
    }
    __syncthreads();

    // Stage Q: A = H (16 rows), B = W2F d-tiles (wave*4+nt). No bias, NO relu.
    f32x4 acc2[4];
    #pragma unroll
    for (int nt = 0; nt < 4; ++nt) acc2[nt] = zero4;
    #pragma unroll
    for (int ks = 0; ks < 8; ++ks) {
        bf16x8 af = *(const bf16x8*)(&sPE[(ks * 64 + lane) * 8]);
        #pragma unroll
        for (int nt = 0; nt < 4; ++nt) {
            bf16x8 bw = *(const bf16x8*)(w2f + (size_t)(((wave * 4 + nt) * 8 + ks) * 64 + lane) * 8);
            acc2[nt] = mfma16(af, bw, acc2[nt]);
        }
    }
    #pragma unroll
    for (int nt = 0; nt < 4; ++nt) {
        int d = (wave * 4 + nt) * 16 + l15;
        #pragma unroll
        for (int r = 0; r < 4; ++r) {
            int rl = quad * 4 + r;
            if (row0 + rl < dim)
                Qt[qBase + (size_t)(row0 + rl) * 256 + d] = (bf16)acc2[nt][r];
        }
    }
}

// ---- main: h2 = relu(Q0[i0]+Q1[i1]+Q2[i2]+b2); h3 = relu(h2 Wfc1^T + bfc1);
// ---- out = relu(h3.wfc2 + bfc2). 64 rows/block, ~35 KB LDS, 4 blocks/CU.
// Gather: half-wave per row -> coalesced 512B row reads. wfc1 fragment-ordered.
// Stage D: per-wave partial slots (no LDS atomics).
__global__ __launch_bounds__(256, 4)
void costco_main(const bf16* __restrict__ wsb, const bf16* __restrict__ Qt,
                 const float* __restrict__ wsf, const int* __restrict__ flagp,
                 const int* __restrict__ idx32, void* __restrict__ out)
{
    __shared__ alignas(16) bf16 sH2[BT * 264];
    __shared__ float sPart[4][BT];
    __shared__ int sIdx[BT * 3];

    const bf16* wf   = wsb + O_F1;   // fragment-ordered wfc1
    const bf16* wfc2 = wsb + O_F2;
    const float* fb2  = wsf + 256;
    const float* fbc1 = wsf + 512;
    const float  bfc2v = wsf[768];
    const int fp32out = *flagp;

    const int tid  = threadIdx.x;
    const int wave = tid >> 6;
    const int lane = tid & 63;
    const int quad = lane >> 4;
    const int l15  = lane & 15;
    const int bbase = blockIdx.x * BT;

    if (tid < BT * 3) sIdx[tid] = idx32[bbase * 3 + tid];
    __syncthreads();

    // gather + sum + bias + relu -> sH2. Half-wave (32 lanes) per row.
    {
        const int half = lane >> 5;
        const int l31  = lane & 31;
        float bb[8];
        {
            float4 t0 = *(const float4*)(fb2 + l31 * 8);
            float4 t1 = *(const float4*)(fb2 + l31 * 8 + 4);
            bb[0]=t0.x; bb[1]=t0.y; bb[2]=t0.z; bb[3]=t0.w;
            bb[4]=t1.x; bb[5]=t1.y; bb[6]=t1.z; bb[7]=t1.w;
        }
        #pragma unroll
        for (int rp = 0; rp < 8; ++rp) {
            const int r  = wave * 16 + rp * 2 + half;
            const int i0 = sIdx[r * 3 + 0];
            const int i1 = sIdx[r * 3 + 1];
            const int i2 = sIdx[r * 3 + 2];
            bf16x8 a = *(const bf16x8*)(Qt + QB0 + (size_t)i0 * 256 + l31 * 8);
            bf16x8 b = *(const bf16x8*)(Qt + QB1 + (size_t)i1 * 256 + l31 * 8);
            bf16x8 c = *(const bf16x8*)(Qt + QB2 + (size_t)i2 * 256 + l31 * 8);
            bf16x8 o;
            #pragma unroll
            for (int j = 0; j < 8; ++j) {
                float v = (float)a[j] + (float)b[j] + (float)c[j] + bb[j];
                o[j] = (bf16)fmaxf(v, 0.f);
            }
            *(bf16x8*)(&sH2[r * 264 + l31 * 8]) = o;
        }
    }
    __syncthreads();

    const f32x4 zero4 = {0.f, 0.f, 0.f, 0.f};

    // Stage C: h3 = relu(h2 Wfc1^T + bfc1), waves split N(e).
    f32x4 acc3[4][4];
    #pragma unroll
    for (int i = 0; i < 4; ++i)
        #pragma unroll
        for (int j = 0; j < 4; ++j) acc3[i][j] = zero4;
    #pragma unroll
    for (int ks = 0; ks < 8; ++ks) {
        bf16x8 af[4], bfr[4];
        #pragma unroll
        for (int mt = 0; mt < 4; ++mt)
            af[mt] = *(const bf16x8*)(&sH2[(mt * 16 + l15) * 264 + ks * 32 + quad * 8]);
        #pragma unroll
        for (int nt = 0; nt < 4; ++nt)
            bfr[nt] = *(const bf16x8*)(wf + ((size_t)((wave * 4 + nt) * 8 + ks) * 64 + lane) * 8);
        #pragma unroll
        for (int mt = 0; mt < 4; ++mt)
            #pragma unroll
            for (int nt = 0; nt < 4; ++nt)
                acc3[mt][nt] = mfma16(af[mt], bfr[nt], acc3[mt][nt]);
    }

    // Stage D: per-wave partial into sPart, then one reduction pass.
    float wv[4], bc[4];
    #pragma unroll
    for (int nt = 0; nt < 4; ++nt) {
        int e = wave * 64 + nt * 16 + l15;
        wv[nt] = (float)wfc2[e];
        bc[nt] = fbc1[e];
    }
    #pragma unroll
    for (int mt = 0; mt < 4; ++mt)
        #pragma unroll
        for (int r = 0; r < 4; ++r) {
            float p = 0.f;
            #pragma unroll
            for (int nt = 0; nt < 4; ++nt)
                p += fmaxf(acc3[mt][nt][r] + bc[nt], 0.f) * wv[nt];
            p += __shfl_xor(p, 1, 64);
            p += __shfl_xor(p, 2, 64);
            p += __shfl_xor(p, 4, 64);
            p += __shfl_xor(p, 8, 64);
            if (l15 == 0) sPart[wave][mt * 16 + quad * 4 + r] = p;
        }
    __syncthreads();

    if (tid < BT) {
        float v = sPart[0][tid] + sPart[1][tid] + sPart[2][tid] + sPart[3][tid] + bfc2v;
        v = fmaxf(v, 0.f);
        if (fp32out) ((float*)out)[bbase + tid] = v;
        else         ((bf16*)out)[bbase + tid] = (bf16)v;
    }
}

extern "C" void kernel_launch(void* const* d_in, const int* in_sizes, int n_in,
                              void* d_out, int out_size, void* d_ws, size_t ws_size,
                              hipStream_t stream) {
    char* ws = (char*)d_ws;
    bf16*  wsb   = (bf16*)ws;
    float* wsf   = (float*)(ws + OFF_FLOAT);
    int*   flagp = (int*)(ws + OFF_FLAG);
    int*   idx32 = (int*)(ws + OFF_IDX);
    bf16*  Qt    = (bf16*)(ws + OFF_Q);

    hipLaunchKernelGGL(convert_all, dim3(1009), dim3(256), 0, stream,
                       d_in[1], d_in[2], d_in[3], d_in[4], d_in[5], d_in[6],
                       d_in[7], d_in[8], d_in[9], d_in[10], d_in[11], d_in[0],
                       wsb, wsf, flagp, idx32);

    hipLaunchKernelGGL(build_q, dim3(391), dim3(256), 0, stream, wsb, wsf, Qt);

    const int B = 131072;
    hipLaunchKernelGGL(costco_main, dim3(B / BT), dim3(256), 0, stream,
                       wsb, Qt, wsf, flagp, idx32, d_out);
}

// Round 4
// 117.779 us; speedup vs baseline: 1.4002x; 1.0005x over previous
//
#include <hip/hip_runtime.h>

typedef __bf16 bf16;
typedef __bf16 bf16x4 __attribute__((ext_vector_type(4)));
typedef __bf16 bf16x8 __attribute__((ext_vector_type(8)));
typedef float  f32x4  __attribute__((ext_vector_type(4)));
typedef unsigned int uint32;

#define BT 64

// ---- bf16 workspace layout (element offsets) ----
// All build_q operands stored in MFMA-fragment order:
//   frag(ee,kk,NKS): (((ee>>4)*NKS + (kk>>5))*64 + ((kk>>3)&3)*16 + (ee&15))*8 + (kk&7)
// EF*: emb tables, 16-row tiles (2048 elems/tile), padded to tile count.
#define N_EF0 (22*2048)
#define N_EF1 (365*2048)
#define N_EF2 (4*2048)
#define O_EF0 0
#define O_EF1 (O_EF0+N_EF0)      // 45056
#define O_EF2 (O_EF1+N_EF1)      // 792576
#define O_W1F (O_EF2+N_EF2)      // 800768  w1 fragment order (NKS=4)
#define O_W2F (O_W1F+32768)      // 833536  w2 per-mode fragment order [m][dt][ks][lane][8]
#define O_F1  (O_W2F+196608)     // 1030144 wfc1 fragment order (NKS=8)
#define O_F2  (O_F1+65536)       // 1095680 wfc2
#define N_TOT (O_F2+256)         // 1095936 bf16

#define BYTES_BF16 ((size_t)N_TOT*2)
#define OFF_FLOAT  BYTES_BF16              // f32: b1(256) b2(256) bfc1(256) bfc2(1)
#define OFF_FLAG   (OFF_FLOAT + 772*4)
#define OFF_IDX    (OFF_FLAG + 16)         // int32 idx (131072*3)
#define N_IDX      (131072*3)
#define OFF_Q      (OFF_IDX + (size_t)N_IDX*4)

// Q tables (bf16): Q_m[i][d], 6228 rows total -> 3.19 MB (L2-resident)
// b2 is folded into Q0 at build time.
#define QB0 0
#define QB1 (339*256)
#define QB2 (QB1 + 5825*256)

static __device__ __forceinline__ f32x4 mfma16(bf16x8 a, bf16x8 b, f32x4 c) {
    return __builtin_amdgcn_mfma_f32_16x16x32_bf16(a, b, c, 0, 0, 0);
}

static __device__ __forceinline__ unsigned frag_off(unsigned ee, unsigned kk, unsigned nks) {
    return (((ee >> 4) * nks + (kk >> 5)) * 64u + ((kk >> 3) & 3u) * 16u + (ee & 15u)) * 8u
           + (kk & 7u);
}

// ---- normalization. Block ranges: [0,256) idx; [256,768) fragment-copy;
// [768,1008) w2 fragment-transpose; 1008 biases+flag.
__global__ __launch_bounds__(256)
void convert_all(const void* __restrict__ e0, const void* __restrict__ e1,
                 const void* __restrict__ e2, const void* __restrict__ w1r,
                 const void* __restrict__ b1r, const void* __restrict__ w2r,
                 const void* __restrict__ b2r, const void* __restrict__ f1r,
                 const void* __restrict__ fc1br, const void* __restrict__ f2r,
                 const void* __restrict__ fc2br, const void* __restrict__ idxr,
                 bf16* __restrict__ wsb, float* __restrict__ wsf,
                 int* __restrict__ flagp, int* __restrict__ idx32)
{
    __shared__ int sF;
    const int tid = threadIdx.x;
    const int bid = blockIdx.x;
    if (tid == 0) sF = 0;
    __syncthreads();

    if (bid < 256) {
        // i64 probe: int64 index buffers (values < 2^31) have all-zero odd words
        if (((const uint32*)idxr)[tid * 2 + 1] != 0) atomicOr(&sF, 1);
        __syncthreads();
        const bool i64 = (sF == 0);
        #pragma unroll
        for (int it = 0; it < 6; ++it) {
            int k = bid * 1536 + it * 256 + tid;
            if (k < N_IDX) {
                long long v = i64 ? ((const long long*)idxr)[k]
                                  : (long long)((const int*)idxr)[k];
                int m = k - (k / 3) * 3;
                long long dim = (m == 0 ? 339 : (m == 1 ? 5825 : 64));
                v = v < 0 ? 0 : (v >= dim ? dim - 1 : v);
                idx32[k] = (int)v;
            }
        }
        return;
    }

    // fp32 probe: low 16 bits of word as bf16 with exp>126 impossible for |w1|<=0.37
    if (tid < 64) {
        uint32 e = (((const uint32*)w1r)[tid] >> 7) & 0xffu;
        if (e > 126u) atomicOr(&sF, 1);
    }
    __syncthreads();
    const bool fp32 = (sF != 0);

    if (bid < 768) {
        // fragment-copy, source-linear in 4-elt chunks (all region sizes %4==0).
        // cum: e0 43392 | e1 788992 | e2 797184 | w1 829952 | f1 895488 | f2 895744
        const unsigned n4 = 895744u / 4u;
        for (unsigned u = (bid - 256) * 256u + tid; u < n4; u += 512u * 256u) {
            unsigned e = u * 4;
            const void* src; unsigned off, dst;
            if (e < 829952u) {   // emb/w1: fragment NKS=4
                unsigned base;
                if (e < 43392u)       { src = e0;  off = e;           base = O_EF0; }
                else if (e < 788992u) { src = e1;  off = e - 43392u;  base = O_EF1; }
                else if (e < 797184u) { src = e2;  off = e - 788992u; base = O_EF2; }
                else                  { src = w1r; off = e - 797184u; base = O_W1F; }
                dst = base + frag_off(off >> 7, off & 127u, 4u);
            } else if (e < 895488u) {  // wfc1: fragment NKS=8
                src = f1r; off = e - 829952u;
                dst = O_F1 + frag_off(off >> 8, off & 255u, 8u);
            } else {                   // wfc2 straight
                src = f2r; off = e - 895488u; dst = O_F2 + off;
            }
            if (fp32) {
                float4 v = *(const float4*)((const float*)src + off);
                bf16x4 o; o[0]=(bf16)v.x; o[1]=(bf16)v.y; o[2]=(bf16)v.z; o[3]=(bf16)v.w;
                *(bf16x4*)(wsb + dst) = o;
            } else {
                *(uint2*)(wsb + dst) = *(const uint2*)((const bf16*)src + off);
            }
        }
    } else if (bid < 1008) {
        // W2F[m][dt][ks][lane][j] = w2[d][c][m], d=dt*16+(lane&15), c=ks*32+(lane>>4)*8+j
        for (unsigned i = (bid - 768) * 256u + tid; i < 196608u; i += 240u * 256u) {
            unsigned m = i >> 16, r = i & 65535u;
            unsigned dt = r >> 12, ks = (r >> 9) & 7u, lane = (r >> 3) & 63u, j = r & 7u;
            unsigned d = dt * 16u + (lane & 15u);
            unsigned c = ks * 32u + (lane >> 4) * 8u + j;
            unsigned off = d * 768u + c * 3u + m;
            wsb[O_W2F + i] = fp32 ? (bf16)((const float*)w2r)[off] : ((const bf16*)w2r)[off];
        }
    } else {
        if (tid == 0) *flagp = fp32 ? 1 : 0;
        #pragma unroll
        for (int it = 0; it < 4; ++it) {
            int j = it * 256 + tid;
            if (j < 769) {
                const void* src; int off;
                if (j < 256)      { src = b1r;   off = j; }
                else if (j < 512) { src = b2r;   off = j - 256; }
                else if (j < 768) { src = fc1br; off = j - 512; }
                else              { src = fc2br; off = 0; }
                wsf[j] = fp32 ? ((const float*)src)[off] : (float)((const bf16*)src)[off];
            }
        }
    }
}

// ---- build Q tables: Q_m[i][d] = sum_c relu(<emb_m[i],w1[c]>+b1[c]) * w2[d][c][m]
// One 16-row tile per block -> 391 blocks. All global loads lane-linear.
// b2[d] is folded into Q0 (mode 0) so costco's gather needs no bias add.
__global__ __launch_bounds__(256)
void build_q(const bf16* __restrict__ wsb, const float* __restrict__ wsf,
             bf16* __restrict__ Qt)
{
    __shared__ alignas(16) bf16 sPE[4096];

    const int tid  = threadIdx.x;
    const int wave = tid >> 6;
    const int lane = tid & 63;
    const int quad = lane >> 4;
    const int l15  = lane & 15;
    const int bid  = blockIdx.x;

    int m, tile, dim, efBase, qBase;
    if (bid < 22)       { m = 0; tile = bid;       dim = 339;  efBase = O_EF0; qBase = QB0; }
    else if (bid < 387) { m = 1; tile = bid - 22;  dim = 5825; efBase = O_EF1; qBase = QB1; }
    else                { m = 2; tile = bid - 387; dim = 64;   efBase = O_EF2; qBase = QB2; }
    const int row0 = tile * 16;

    const bf16* w1f = wsb + O_W1F;
    const bf16* w2f = wsb + O_W2F + m * 65536;
    const float* fb1 = wsf;
    const float* fb2 = wsf + 256;
    const f32x4 zero4 = {0.f, 0.f, 0.f, 0.f};

    // emb B-fragments for this tile (shared across all mt)
    bf16x8 be[4];
    #pragma unroll
    for (int ks = 0; ks < 4; ++ks)
        be[ks] = *(const bf16x8*)(wsb + efBase + (size_t)((tile * 4 + ks) * 64 + lane) * 8);

    // Stage PE: H[c][row] = relu(w1.emb^T + b1); write into stage-Q A-fragment layout.
    #pragma unroll
    for (int mtl = 0; mtl < 4; ++mtl) {
        int mt = wave * 4 + mtl;
        f32x4 acc = zero4;
        #pragma unroll
        for (int ks = 0; ks < 4; ++ks) {
            bf16x8 aw = *(const bf16x8*)(w1f + ((mt * 4 + ks) * 64 + lane) * 8);
            acc = mfma16(aw, be[ks], acc);
        }
        const float4 bv = *(const float4*)(fb1 + mt * 16 + quad * 4);
        bf16x4 hv;
        hv[0] = (bf16)fmaxf(acc[0] + bv.x, 0.f);
        hv[1] = (bf16)fmaxf(acc[1] + bv.y, 0.f);
        hv[2] = (bf16)fmaxf(acc[2] + bv.z, 0.f);
        hv[3] = (bf16)fmaxf(acc[3] + bv.w, 0.f);
        // element (row=l15, c=mt*16+quad*4+r) -> A-frag (ks=c>>5, quadq=(c>>3)&3, j=c&7)
        int ksq   = mt >> 1;
        int quadq = ((mt & 1) << 1) | (quad >> 1);
        int j0    = (quad & 1) * 4;
        *(bf16x4*)(&sPE[(ksq * 64 + quadq * 16 + l15) * 8 + j0]) = hv;
    }
    __syncthreads();

    // Stage Q: A = H (16 rows), B = W2F d-tiles (wave*4+nt). No relu.
    f32x4 acc2[4];
    #pragma unroll
    for (int nt = 0; nt < 4; ++nt) acc2[nt] = zero4;
    #pragma unroll
    for (int ks = 0; ks < 8; ++ks) {
        bf16x8 af = *(const bf16x8*)(&sPE[(ks * 64 + lane) * 8]);
        #pragma unroll
        for (int nt = 0; nt < 4; ++nt) {
            bf16x8 bw = *(const bf16x8*)(w2f + (size_t)(((wave * 4 + nt) * 8 + ks) * 64 + lane) * 8);
            acc2[nt] = mfma16(af, bw, acc2[nt]);
        }
    }
    #pragma unroll
    for (int nt = 0; nt < 4; ++nt) {
        int d = (wave * 4 + nt) * 16 + l15;
        const float addb = (m == 0) ? fb2[d] : 0.f;   // fold b2 into Q0
        #pragma unroll
        for (int r = 0; r < 4; ++r) {
            int rl = quad * 4 + r;
            if (row0 + rl < dim)
                Qt[qBase + (size_t)(row0 + rl) * 256 + d] = (bf16)(acc2[nt][r] + addb);
        }
    }
}

// ---- main: h2 = relu(Q0'[i0]+Q1[i1]+Q2[i2]); h3 = relu(h2 Wfc1^T + bfc1);
// ---- out = relu(h3.wfc2 + bfc2). 64 rows/block, ~34 KB LDS, 4 blocks/CU.
// sH2 held in XOR-swizzled MFMA-A-fragment order:
//   chunk(mt,ks,quad,l15) = (mt*8+ks)*64 + quad*16 + (l15^ks), 16B chunks.
// Reads (stage C) are a lane-permutation of a contiguous 1KB group -> conflict-free;
// writes (gather) are bank-balanced (8 words/bank). Only 2 barriers.
__global__ __launch_bounds__(256, 4)
void costco_main(const bf16* __restrict__ wsb, const bf16* __restrict__ Qt,
                 const float* __restrict__ wsf, const int* __restrict__ flagp,
                 const int* __restrict__ idx32, void* __restrict__ out)
{
    __shared__ alignas(16) bf16 sH2[BT * 256];
    __shared__ float sPart[4][BT];

    const bf16* wf   = wsb + O_F1;   // fragment-ordered wfc1
    const bf16* wfc2 = wsb + O_F2;
    const float* fbc1 = wsf + 512;
    const float  bfc2v = wsf[768];
    const int fp32out = *flagp;

    const int tid  = threadIdx.x;
    const int wave = tid >> 6;
    const int lane = tid & 63;
    const int quad = lane >> 4;
    const int l15  = lane & 15;
    const int bbase = blockIdx.x * BT;

    // ---- gather: half-wave per row, idx loaded straight to registers ----
    {
        const int half  = lane >> 5;
        const int l31   = lane & 31;
        const int ksw   = l31 >> 2;
        const int quadw = l31 & 3;
        int i0[8], i1[8], i2[8];
        #pragma unroll
        for (int rp = 0; rp < 8; ++rp) {
            const int gb = (bbase + wave * 16 + rp * 2 + half) * 3;
            i0[rp] = idx32[gb];
            i1[rp] = idx32[gb + 1];
            i2[rp] = idx32[gb + 2];
        }
        #pragma unroll
        for (int rp = 0; rp < 8; ++rp) {
            bf16x8 a = *(const bf16x8*)(Qt + QB0 + (size_t)i0[rp] * 256 + l31 * 8);
            bf16x8 b = *(const bf16x8*)(Qt + QB1 + (size_t)i1[rp] * 256 + l31 * 8);
            bf16x8 c = *(const bf16x8*)(Qt + QB2 + (size_t)i2[rp] * 256 + l31 * 8);
            bf16x8 o;
            #pragma unroll
            for (int j = 0; j < 8; ++j)
                o[j] = (bf16)fmaxf((float)a[j] + (float)b[j] + (float)c[j], 0.f);
            const int l15r = rp * 2 + half;
            *(bf16x8*)(&sH2[((wave * 8 + ksw) * 64 + quadw * 16 + (l15r ^ ksw)) * 8]) = o;
        }
    }

    // hoist ks=0 wfc1 B-fragments above the barrier (L2 latency hides in drain)
    bf16x8 bfr0[4];
    #pragma unroll
    for (int nt = 0; nt < 4; ++nt)
        bfr0[nt] = *(const bf16x8*)(wf + ((size_t)((wave * 4 + nt) * 8) * 64 + lane) * 8);

    __syncthreads();

    const f32x4 zero4 = {0.f, 0.f, 0.f, 0.f};

    // Stage C: h3 = relu(h2 Wfc1^T + bfc1), waves split N(e).
    f32x4 acc3[4][4];
    #pragma unroll
    for (int i = 0; i < 4; ++i)
        #pragma unroll
        for (int j = 0; j < 4; ++j) acc3[i][j] = zero4;
    #pragma unroll
    for (int ks = 0; ks < 8; ++ks) {
        bf16x8 af[4], bfr[4];
        #pragma unroll
        for (int mt = 0; mt < 4; ++mt)
            af[mt] = *(const bf16x8*)(&sH2[((mt * 8 + ks) * 64 + quad * 16 + (l15 ^ ks)) * 8]);
        #pragma unroll
        for (int nt = 0; nt < 4; ++nt)
            bfr[nt] = (ks == 0) ? bfr0[nt]
                    : *(const bf16x8*)(wf + ((size_t)((wave * 4 + nt) * 8 + ks) * 64 + lane) * 8);
        #pragma unroll
        for (int mt = 0; mt < 4; ++mt)
            #pragma unroll
            for (int nt = 0; nt < 4; ++nt)
                acc3[mt][nt] = mfma16(af[mt], bfr[nt], acc3[mt][nt]);
    }

    // Stage D: per-wave partial into sPart, then one reduction pass.
    float wv[4], bc[4];
    #pragma unroll
    for (int nt = 0; nt < 4; ++nt) {
        int e = wave * 64 + nt * 16 + l15;
        wv[nt] = (float)wfc2[e];
        bc[nt] = fbc1[e];
    }
    #pragma unroll
    for (int mt = 0; mt < 4; ++mt)
        #pragma unroll
        for (int r = 0; r < 4; ++r) {
            float p = 0.f;
            #pragma unroll
            for (int nt = 0; nt < 4; ++nt)
                p += fmaxf(acc3[mt][nt][r] + bc[nt], 0.f) * wv[nt];
            p += __shfl_xor(p, 1, 64);
            p += __shfl_xor(p, 2, 64);
            p += __shfl_xor(p, 4, 64);
            p += __shfl_xor(p, 8, 64);
            if (l15 == 0) sPart[wave][mt * 16 + quad * 4 + r] = p;
        }
    __syncthreads();

    if (tid < BT) {
        float v = sPart[0][tid] + sPart[1][tid] + sPart[2][tid] + sPart[3][tid] + bfc2v;
        v = fmaxf(v, 0.f);
        if (fp32out) ((float*)out)[bbase + tid] = v;
        else         ((bf16*)out)[bbase + tid] = (bf16)v;
    }
}

extern "C" void kernel_launch(void* const* d_in, const int* in_sizes, int n_in,
                              void* d_out, int out_size, void* d_ws, size_t ws_size,
                              hipStream_t stream) {
    char* ws = (char*)d_ws;
    bf16*  wsb   = (bf16*)ws;
    float* wsf   = (float*)(ws + OFF_FLOAT);
    int*   flagp = (int*)(ws + OFF_FLAG);
    int*   idx32 = (int*)(ws + OFF_IDX);
    bf16*  Qt    = (bf16*)(ws + OFF_Q);

    hipLaunchKernelGGL(convert_all, dim3(1009), dim3(256), 0, stream,
                       d_in[1], d_in[2], d_in[3], d_in[4], d_in[5], d_in[6],
                       d_in[7], d_in[8], d_in[9], d_in[10], d_in[11], d_in[0],
                       wsb, wsf, flagp, idx32);

    hipLaunchKernelGGL(build_q, dim3(391), dim3(256), 0, stream, wsb, wsf, Qt);

    const int B = 131072;
    hipLaunchKernelGGL(costco_main, dim3(B / BT), dim3(256), 0, stream,
                       wsb, Qt, wsf, flagp, idx32, d_out);
}